// Round 13
// baseline (201.614 us; speedup 1.0000x reference)
//
#include <hip/hip_runtime.h>

#define NN 50000
#define NE 800000
#define SLOTS 64

typedef float f32x4 __attribute__((ext_vector_type(4)));
typedef short short8 __attribute__((ext_vector_type(8)));

static __device__ __forceinline__ unsigned short f2bf(float f){
  unsigned u = __builtin_bit_cast(unsigned, f);
  u = (u + 0x7fffu + ((u >> 16) & 1u)) >> 16;
  return (unsigned short)u;
}
static __device__ __forceinline__ float bf2f(unsigned short b){
  return __builtin_bit_cast(float, ((unsigned)b) << 16);
}

// ---------- prep + scatter fused (cnt pre-zeroed by hipMemsetAsync) ----------
__global__ __launch_bounds__(256) void k_prep(
    const float* __restrict__ x, const int* __restrict__ ei,
    const float* __restrict__ W1m, const float* __restrict__ b1m,
    const float* __restrict__ W1e, const float* __restrict__ b1e,
    const float* __restrict__ W1s, const float* __restrict__ b1s,
    const float* __restrict__ W2m, const float* __restrict__ b2m,
    const float* __restrict__ W2e, const float* __restrict__ b2e,
    const float* __restrict__ W2s, const float* __restrict__ b2s,
    int* __restrict__ cnt,
    int* __restrict__ srcs_pad, int* __restrict__ eids_pad,
    unsigned short* __restrict__ xb,
    unsigned short* __restrict__ W1c, unsigned short* __restrict__ W2c,
    unsigned short* __restrict__ W2mb,
    float* __restrict__ b1sA, float* __restrict__ b1dA,
    float* __restrict__ b2sA, float* __restrict__ b2dA)
{
  int g = blockIdx.x*256 + threadIdx.x;
  // --- scatter 8 edges per thread (cnt already zeroed by memset) ---
  {
    int e = g*8;
    if (e + 8 <= NE){
      int4 s0 = *(const int4*)(ei + e);
      int4 s1 = *(const int4*)(ei + e + 4);
      int4 d0 = *(const int4*)(ei + NE + e);
      int4 d1 = *(const int4*)(ei + NE + e + 4);
      int p;
      p = atomicAdd(&cnt[d0.x], 1); if (p < SLOTS){ srcs_pad[d0.x*SLOTS+p]=s0.x; eids_pad[d0.x*SLOTS+p]=e+0; }
      p = atomicAdd(&cnt[d0.y], 1); if (p < SLOTS){ srcs_pad[d0.y*SLOTS+p]=s0.y; eids_pad[d0.y*SLOTS+p]=e+1; }
      p = atomicAdd(&cnt[d0.z], 1); if (p < SLOTS){ srcs_pad[d0.z*SLOTS+p]=s0.z; eids_pad[d0.z*SLOTS+p]=e+2; }
      p = atomicAdd(&cnt[d0.w], 1); if (p < SLOTS){ srcs_pad[d0.w*SLOTS+p]=s0.w; eids_pad[d0.w*SLOTS+p]=e+3; }
      p = atomicAdd(&cnt[d1.x], 1); if (p < SLOTS){ srcs_pad[d1.x*SLOTS+p]=s1.x; eids_pad[d1.x*SLOTS+p]=e+4; }
      p = atomicAdd(&cnt[d1.y], 1); if (p < SLOTS){ srcs_pad[d1.y*SLOTS+p]=s1.y; eids_pad[d1.y*SLOTS+p]=e+5; }
      p = atomicAdd(&cnt[d1.z], 1); if (p < SLOTS){ srcs_pad[d1.z*SLOTS+p]=s1.z; eids_pad[d1.z*SLOTS+p]=e+6; }
      p = atomicAdd(&cnt[d1.w], 1); if (p < SLOTS){ srcs_pad[d1.w*SLOTS+p]=s1.w; eids_pad[d1.w*SLOTS+p]=e+7; }
    } else if (e < NE){
      for (int q=e; q<NE; q++){
        int s = ei[q], d = ei[NE+q];
        int pos = atomicAdd(&cnt[d], 1);
        if (pos < SLOTS){ srcs_pad[d*SLOTS+pos] = s; eids_pad[d*SLOTS+pos] = q; }
      }
    }
  }
  // --- prep ---
  if (g < NN*8){
    const float4* xp = (const float4*)x;
    float4 v0 = xp[(size_t)g*2], v1 = xp[(size_t)g*2+1];
    short8 o;
    o[0]=(short)f2bf(v0.x); o[1]=(short)f2bf(v0.y); o[2]=(short)f2bf(v0.z); o[3]=(short)f2bf(v0.w);
    o[4]=(short)f2bf(v1.x); o[5]=(short)f2bf(v1.y); o[6]=(short)f2bf(v1.z); o[7]=(short)f2bf(v1.w);
    *(short8*)(xb + (size_t)g*8) = o;
  }
  if (g < 256*192){
    int oc = g/192, k = g%192;
    float w = (k<64)? W1m[oc*64+k] : (k<128)? W1e[oc*64+(k-64)] : W1s[oc*64+(k-128)];
    W1c[g] = f2bf(w);
  }
  if (g < 64*320){
    int oc = g/320, k = g%320;
    float w = (k<64)? W2e[oc*64+k] : W2s[oc*256+(k-64)];
    W2c[g] = f2bf(w);
  }
  if (g < 64*256){
    W2mb[g] = f2bf(W2m[g]);
  }
  if (g < 256){ b1sA[g] = b1s[g]; b1dA[g] = b1m[g] + b1e[g]; }
  if (g < 64) { b2sA[g] = b2s[g]; b2dA[g] = b2m[g] + b2e[g]; }
}

// ---------- phase A: per-dst sums of x[src] (bf16) and edge_attr (f32, NT) -> bf16 in1[NN][128] ----------
__global__ __launch_bounds__(256) void k_aggA(const int* __restrict__ srcs, const int* __restrict__ eids,
    const int* __restrict__ cnt,
    const unsigned short* __restrict__ xb, const float* __restrict__ ea,
    unsigned short* __restrict__ in1){
  int v = blockIdx.x*4 + (threadIdx.x>>6);
  int lane = threadIdx.x & 63;
  int slot = lane >> 4, fg = lane & 15;
  if (v >= NN) return;
  int beg = v*SLOTS;
  int end = beg + min(cnt[v], SLOTS);
  float xs[4] = {0,0,0,0}, es[4] = {0,0,0,0};
  float xt[4] = {0,0,0,0}, et[4] = {0,0,0,0};
  int i = beg + slot;
  for (; i + 12 < end; i += 16){
    int q0=eids[i], q1=eids[i+4], q2=eids[i+8], q3=eids[i+12];
    int s0=srcs[i], s1=srcs[i+4], s2=srcs[i+8], s3=srcs[i+12];
    f32x4 ev0 = __builtin_nontemporal_load((const f32x4*)(ea + (size_t)q0*64 + fg*4));
    f32x4 ev1 = __builtin_nontemporal_load((const f32x4*)(ea + (size_t)q1*64 + fg*4));
    f32x4 ev2 = __builtin_nontemporal_load((const f32x4*)(ea + (size_t)q2*64 + fg*4));
    f32x4 ev3 = __builtin_nontemporal_load((const f32x4*)(ea + (size_t)q3*64 + fg*4));
    ushort4 xv0 = *(const ushort4*)(xb + (size_t)s0*64 + fg*4);
    ushort4 xv1 = *(const ushort4*)(xb + (size_t)s1*64 + fg*4);
    ushort4 xv2 = *(const ushort4*)(xb + (size_t)s2*64 + fg*4);
    ushort4 xv3 = *(const ushort4*)(xb + (size_t)s3*64 + fg*4);
    es[0]+=ev0[0]; es[1]+=ev0[1]; es[2]+=ev0[2]; es[3]+=ev0[3];
    et[0]+=ev1[0]; et[1]+=ev1[1]; et[2]+=ev1[2]; et[3]+=ev1[3];
    es[0]+=ev2[0]; es[1]+=ev2[1]; es[2]+=ev2[2]; es[3]+=ev2[3];
    et[0]+=ev3[0]; et[1]+=ev3[1]; et[2]+=ev3[2]; et[3]+=ev3[3];
    xs[0]+=bf2f(xv0.x); xs[1]+=bf2f(xv0.y); xs[2]+=bf2f(xv0.z); xs[3]+=bf2f(xv0.w);
    xt[0]+=bf2f(xv1.x); xt[1]+=bf2f(xv1.y); xt[2]+=bf2f(xv1.z); xt[3]+=bf2f(xv1.w);
    xs[0]+=bf2f(xv2.x); xs[1]+=bf2f(xv2.y); xs[2]+=bf2f(xv2.z); xs[3]+=bf2f(xv2.w);
    xt[0]+=bf2f(xv3.x); xt[1]+=bf2f(xv3.y); xt[2]+=bf2f(xv3.z); xt[3]+=bf2f(xv3.w);
  }
  for (; i < end; i += 4){
    int q0 = eids[i], s0 = srcs[i];
    f32x4  ev0 = __builtin_nontemporal_load((const f32x4*)(ea + (size_t)q0*64 + fg*4));
    ushort4 xv0 = *(const ushort4*)(xb + (size_t)s0*64 + fg*4);
    es[0]+=ev0[0]; es[1]+=ev0[1]; es[2]+=ev0[2]; es[3]+=ev0[3];
    xs[0]+=bf2f(xv0.x); xs[1]+=bf2f(xv0.y); xs[2]+=bf2f(xv0.z); xs[3]+=bf2f(xv0.w);
  }
  #pragma unroll
  for (int k=0;k<4;k++){
    float a = xs[k] + xt[k];
    float b = es[k] + et[k];
    a += __shfl_xor(a, 16, 64); a += __shfl_xor(a, 32, 64);
    b += __shfl_xor(b, 16, 64); b += __shfl_xor(b, 32, 64);
    xs[k] = a; es[k] = b;
  }
  if (slot == 0){
    unsigned short* o = in1 + (size_t)v*128;
    ushort4 ox; ox.x=f2bf(xs[0]); ox.y=f2bf(xs[1]); ox.z=f2bf(xs[2]); ox.w=f2bf(xs[3]);
    ushort4 oe; oe.x=f2bf(es[0]); oe.y=f2bf(es[1]); oe.z=f2bf(es[2]); oe.w=f2bf(es[3]);
    *(ushort4*)(o + fg*4)      = ox;
    *(ushort4*)(o + 64 + fg*4) = oe;
  }
}

// ---------- mega kernel: h (LDS) = relu([in1|xb]@W1c^T + ...); y2 = h@W2m^T; z = h@W2s^T + ea@W2e^T + b2 folds ----------
// swizzled LDS: byte = (row*512 + col*2) ^ ((row&7)<<4)
__global__ __launch_bounds__(256) void k_mega(
  const unsigned short* __restrict__ in1, const unsigned short* __restrict__ xb,
  const unsigned short* __restrict__ W1c,
  const unsigned short* __restrict__ W2mb, const unsigned short* __restrict__ W2c,
  const float* __restrict__ b1sA, const float* __restrict__ b1dA,
  const float* __restrict__ b2sA, const float* __restrict__ b2dA,
  const int* __restrict__ cnt,
  unsigned short* __restrict__ y2, float* __restrict__ z)
{
  __shared__ char hl[64*256*2];
  const int tid = threadIdx.x;
  const int w = tid >> 6, l = tid & 63;
  const int lrow = l & 15, lgrp = l >> 4;
  const int n0 = blockIdx.x * 64;
  const int c0 = w * 64;

  // ----- phase 1: layer-1 GEMM -----
  f32x4 acc[4][4];
  #pragma unroll
  for (int i=0;i<4;i++)
    #pragma unroll
    for (int j=0;j<4;j++) acc[i][j] = (f32x4)0.f;

  #pragma unroll 2
  for (int ks=0; ks<6; ks++){
    short8 a[4], b[4];
    #pragma unroll
    for (int rf=0; rf<4; rf++){
      int row = n0 + rf*16 + lrow; if (row >= NN) row = NN-1;
      if (ks < 4) a[rf] = *(const short8*)(in1 + (size_t)row*128 + ks*32 + lgrp*8);
      else        a[rf] = *(const short8*)(xb  + (size_t)row*64 + (ks-4)*32 + lgrp*8);
    }
    #pragma unroll
    for (int cf=0; cf<4; cf++){
      b[cf] = *(const short8*)(W1c + (c0 + cf*16 + lrow)*192 + ks*32 + lgrp*8);
    }
    #pragma unroll
    for (int rf=0; rf<4; rf++)
      #pragma unroll
      for (int cf=0; cf<4; cf++)
        acc[rf][cf] = __builtin_amdgcn_mfma_f32_16x16x32_bf16(a[rf], b[cf], acc[rf][cf], 0, 0, 0);
  }

  float dg[4][4];
  #pragma unroll
  for (int rf=0; rf<4; rf++)
    #pragma unroll
    for (int r=0; r<4; r++){
      int node = n0 + rf*16 + 4*lgrp + r;
      dg[rf][r] = (node < NN) ? (float)cnt[node] : 0.f;
    }

  #pragma unroll
  for (int cf=0; cf<4; cf++){
    int oc = c0 + cf*16 + lrow;
    float bs = b1sA[oc], bd = b1dA[oc];
    #pragma unroll
    for (int rf=0; rf<4; rf++){
      #pragma unroll
      for (int r=0; r<4; r++){
        int rloc = rf*16 + 4*lgrp + r;
        float val = acc[rf][cf][r] + bs + dg[rf][r]*bd;
        val = fmaxf(val, 0.f);
        int byte = (rloc*512 + oc*2) ^ ((rloc & 7) << 4);
        *(unsigned short*)(hl + byte) = f2bf(val);
      }
    }
  }
  __syncthreads();

  // ----- phase 2: y2 = h@W2m^T ; z = h@W2s^T + ea@W2e^T (wave w -> cols w*16..w*16+15) -----
  const int oc2 = w*16 + lrow;
  f32x4 ay[4], az[4];
  #pragma unroll
  for (int i=0;i<4;i++){ ay[i] = (f32x4)0.f; az[i] = (f32x4)0.f; }

  #pragma unroll 2
  for (int ks=0; ks<8; ks++){
    short8 a2[4];
    #pragma unroll
    for (int rf=0; rf<4; rf++){
      int rloc = rf*16 + lrow;
      int byte = (rloc*512 + (ks*32 + lgrp*8)*2) ^ ((rloc & 7) << 4);
      a2[rf] = *(const short8*)(hl + byte);
    }
    short8 by = *(const short8*)(W2mb + oc2*256 + ks*32 + lgrp*8);
    short8 bz = *(const short8*)(W2c  + oc2*320 + 64 + ks*32 + lgrp*8);
    #pragma unroll
    for (int rf=0; rf<4; rf++){
      ay[rf] = __builtin_amdgcn_mfma_f32_16x16x32_bf16(a2[rf], by, ay[rf], 0, 0, 0);
      az[rf] = __builtin_amdgcn_mfma_f32_16x16x32_bf16(a2[rf], bz, az[rf], 0, 0, 0);
    }
  }
  #pragma unroll
  for (int ks=0; ks<2; ks++){
    short8 a3[4];
    #pragma unroll
    for (int rf=0; rf<4; rf++){
      int row = n0 + rf*16 + lrow; if (row >= NN) row = NN-1;
      a3[rf] = *(const short8*)(in1 + (size_t)row*128 + 64 + ks*32 + lgrp*8);
    }
    short8 be = *(const short8*)(W2c + oc2*320 + ks*32 + lgrp*8);
    #pragma unroll
    for (int rf=0; rf<4; rf++)
      az[rf] = __builtin_amdgcn_mfma_f32_16x16x32_bf16(a3[rf], be, az[rf], 0, 0, 0);
  }

  float bs2 = b2sA[oc2], bd2 = b2dA[oc2];
  #pragma unroll
  for (int rf=0; rf<4; rf++){
    #pragma unroll
    for (int r=0; r<4; r++){
      int node = n0 + rf*16 + 4*lgrp + r;
      if (node < NN){
        y2[(size_t)node*64 + oc2] = f2bf(ay[rf][r]);
        z[(size_t)node*64 + oc2]  = az[rf][r] + bs2 + dg[rf][r]*bd2;
      }
    }
  }
}

// ---------- final: agg2 = per-dst sum of y2[src]; out = relu(z + agg2) ----------
__global__ __launch_bounds__(256) void k_aggC(const int* __restrict__ srcs, const int* __restrict__ cnt,
    const unsigned short* __restrict__ y2, const float* __restrict__ z, float* __restrict__ out){
  int v = blockIdx.x*4 + (threadIdx.x>>6);
  int lane = threadIdx.x & 63;
  int slot = lane >> 3, fg = lane & 7;
  if (v >= NN) return;
  int beg = v*SLOTS;
  int end = beg + min(cnt[v], SLOTS);
  float a[8] = {0,0,0,0,0,0,0,0}, b[8] = {0,0,0,0,0,0,0,0};
  int i = beg + slot;
  for (; i + 8 < end; i += 16){
    int s0 = srcs[i], s1 = srcs[i+8];
    short8 y0 = *(const short8*)(y2 + (size_t)s0*64 + fg*8);
    short8 y1 = *(const short8*)(y2 + (size_t)s1*64 + fg*8);
    #pragma unroll
    for (int k=0;k<8;k++){ a[k]+=bf2f((unsigned short)y0[k]); b[k]+=bf2f((unsigned short)y1[k]); }
  }
  for (; i < end; i += 8){
    int s0 = srcs[i];
    short8 y0 = *(const short8*)(y2 + (size_t)s0*64 + fg*8);
    #pragma unroll
    for (int k=0;k<8;k++) a[k]+=bf2f((unsigned short)y0[k]);
  }
  #pragma unroll
  for (int k=0;k<8;k++){
    float t = a[k] + b[k];
    t += __shfl_xor(t, 8, 64); t += __shfl_xor(t, 16, 64); t += __shfl_xor(t, 32, 64);
    a[k] = t;
  }
  if (slot == 0){
    const float4 z0 = *(const float4*)(z + (size_t)v*64 + fg*8);
    const float4 z1 = *(const float4*)(z + (size_t)v*64 + fg*8 + 4);
    f32x4 o0, o1;
    o0[0] = fmaxf(z0.x + a[0], 0.f); o0[1] = fmaxf(z0.y + a[1], 0.f);
    o0[2] = fmaxf(z0.z + a[2], 0.f); o0[3] = fmaxf(z0.w + a[3], 0.f);
    o1[0] = fmaxf(z1.x + a[4], 0.f); o1[1] = fmaxf(z1.y + a[5], 0.f);
    o1[2] = fmaxf(z1.z + a[6], 0.f); o1[3] = fmaxf(z1.w + a[7], 0.f);
    __builtin_nontemporal_store(o0, (f32x4*)(out + (size_t)v*64 + fg*8));
    __builtin_nontemporal_store(o1, (f32x4*)(out + (size_t)v*64 + fg*8 + 4));
  }
}

extern "C" void kernel_launch(void* const* d_in, const int* in_sizes, int n_in,
                              void* d_out, int out_size, void* d_ws, size_t ws_size,
                              hipStream_t stream){
  const float* x   = (const float*)d_in[0];
  const int*   ei  = (const int*)d_in[1];
  const float* ea  = (const float*)d_in[2];
  const float* W1m = (const float*)d_in[3];  const float* b1m = (const float*)d_in[4];
  const float* W1e = (const float*)d_in[5];  const float* b1e = (const float*)d_in[6];
  const float* W1s = (const float*)d_in[7];  const float* b1s = (const float*)d_in[8];
  const float* W2m = (const float*)d_in[9];  const float* b2m = (const float*)d_in[10];
  const float* W2e = (const float*)d_in[11]; const float* b2e = (const float*)d_in[12];
  const float* W2s = (const float*)d_in[13]; const float* b2s = (const float*)d_in[14];
  float* out = (float*)d_out;

  char* base = (char*)d_ws;
  size_t off = 0;
  auto alloc = [&](size_t bytes)->void* {
    void* r = base + off;
    off += (bytes + 255) & ~(size_t)255;
    return r;
  };
  int*   cnt       = (int*)  alloc((size_t)NN*4);
  int*   srcs_pad  = (int*)  alloc(((size_t)NN*SLOTS + SLOTS)*4);
  int*   eids_pad  = (int*)  alloc(((size_t)NN*SLOTS + SLOTS)*4);
  unsigned short* in1 = (unsigned short*)alloc((size_t)NN*128*2);   // [xs|ea] bf16
  unsigned short* y2  = (unsigned short*)alloc((size_t)NN*64*2);
  float*          z   = (float*)         alloc((size_t)NN*64*4);
  unsigned short* xb  = (unsigned short*)alloc((size_t)NN*64*2);
  unsigned short* W1c = (unsigned short*)alloc((size_t)256*192*2);
  unsigned short* W2c = (unsigned short*)alloc((size_t)64*320*2);
  unsigned short* W2mb= (unsigned short*)alloc((size_t)64*256*2);
  float* b1sA = (float*)alloc(256*4);
  float* b1dA = (float*)alloc(256*4);
  float* b2sA = (float*)alloc(64*4);
  float* b2dA = (float*)alloc(64*4);

  hipMemsetAsync(cnt, 0, (size_t)NN*4, stream);
  k_prep  <<<(NN*8+255)/256, 256, 0, stream>>>(x, ei, W1m,b1m,W1e,b1e,W1s,b1s,
                                             W2m,b2m,W2e,b2e,W2s,b2s,
                                             cnt, srcs_pad, eids_pad, xb, W1c, W2c, W2mb,
                                             b1sA,b1dA,b2sA,b2dA);
  k_aggA  <<<(NN+3)/4, 256, 0, stream>>>(srcs_pad, eids_pad, cnt, xb, ea, in1);
  k_mega  <<<(NN+63)/64, 256, 0, stream>>>(in1, xb, W1c, W2mb, W2c,
                                           b1sA, b1dA, b2sA, b2dA, cnt, y2, z);
  k_aggC  <<<(NN+3)/4, 256, 0, stream>>>(srcs_pad, cnt, y2, z, out);
}

// Round 14
// 180.376 us; speedup vs baseline: 1.1177x; 1.1177x over previous
//
#include <hip/hip_runtime.h>

#define NN 50000
#define NE 800000
#define SLOTS 64

typedef float f32x4 __attribute__((ext_vector_type(4)));
typedef short short8 __attribute__((ext_vector_type(8)));

static __device__ __forceinline__ unsigned short f2bf(float f){
  unsigned u = __builtin_bit_cast(unsigned, f);
  u = (u + 0x7fffu + ((u >> 16) & 1u)) >> 16;
  return (unsigned short)u;
}
static __device__ __forceinline__ float bf2f(unsigned short b){
  return __builtin_bit_cast(float, ((unsigned)b) << 16);
}

// ---------- prep: zero cnt + bf16 weight concat + x->bf16 + bias folds ----------
__global__ __launch_bounds__(256) void k_prep(
    const float* __restrict__ x,
    const float* __restrict__ W1m, const float* __restrict__ b1m,
    const float* __restrict__ W1e, const float* __restrict__ b1e,
    const float* __restrict__ W1s, const float* __restrict__ b1s,
    const float* __restrict__ W2m, const float* __restrict__ b2m,
    const float* __restrict__ W2e, const float* __restrict__ b2e,
    const float* __restrict__ W2s, const float* __restrict__ b2s,
    int* __restrict__ cnt,
    unsigned short* __restrict__ xb,
    unsigned short* __restrict__ W1c, unsigned short* __restrict__ W2c,
    unsigned short* __restrict__ W2mb,
    float* __restrict__ b1sA, float* __restrict__ b1dA,
    float* __restrict__ b2sA, float* __restrict__ b2dA)
{
  int g = blockIdx.x*256 + threadIdx.x;
  if (g < NN*8){
    const float4* xp = (const float4*)x;
    float4 v0 = xp[(size_t)g*2], v1 = xp[(size_t)g*2+1];
    short8 o;
    o[0]=(short)f2bf(v0.x); o[1]=(short)f2bf(v0.y); o[2]=(short)f2bf(v0.z); o[3]=(short)f2bf(v0.w);
    o[4]=(short)f2bf(v1.x); o[5]=(short)f2bf(v1.y); o[6]=(short)f2bf(v1.z); o[7]=(short)f2bf(v1.w);
    *(short8*)(xb + (size_t)g*8) = o;
  }
  if (g < NN) cnt[g] = 0;
  if (g < 256*192){
    int oc = g/192, k = g%192;
    float w = (k<64)? W1m[oc*64+k] : (k<128)? W1e[oc*64+(k-64)] : W1s[oc*64+(k-128)];
    W1c[g] = f2bf(w);
  }
  if (g < 64*320){
    int oc = g/320, k = g%320;
    float w = (k<64)? W2e[oc*64+k] : W2s[oc*256+(k-64)];
    W2c[g] = f2bf(w);
  }
  if (g < 64*256){
    W2mb[g] = f2bf(W2m[g]);
  }
  if (g < 256){ b1sA[g] = b1s[g]; b1dA[g] = b1m[g] + b1e[g]; }
  if (g < 64) { b2sA[g] = b2s[g]; b2dA[g] = b2m[g] + b2e[g]; }
}

// ---------- single-pass padded bucket scatter: pairs_pad[d*SLOTS + slot] = (src, eid) ----------
__global__ __launch_bounds__(256) void k_scatter1(const int* __restrict__ ei, int* __restrict__ cnt,
    int2* __restrict__ pairs_pad){
  int e = (blockIdx.x*256 + threadIdx.x)*4;
  if (e + 4 <= NE){
    int4 s = *(const int4*)(ei + e);
    int4 d = *(const int4*)(ei + NE + e);
    int p0 = atomicAdd(&cnt[d.x], 1); if (p0 < SLOTS) pairs_pad[d.x*SLOTS + p0] = make_int2(s.x, e+0);
    int p1 = atomicAdd(&cnt[d.y], 1); if (p1 < SLOTS) pairs_pad[d.y*SLOTS + p1] = make_int2(s.y, e+1);
    int p2 = atomicAdd(&cnt[d.z], 1); if (p2 < SLOTS) pairs_pad[d.z*SLOTS + p2] = make_int2(s.z, e+2);
    int p3 = atomicAdd(&cnt[d.w], 1); if (p3 < SLOTS) pairs_pad[d.w*SLOTS + p3] = make_int2(s.w, e+3);
  } else {
    for (int q=e; q<NE; q++){
      int s = ei[q], d = ei[NE+q];
      int pos = atomicAdd(&cnt[d], 1);
      if (pos < SLOTS) pairs_pad[d*SLOTS + pos] = make_int2(s, q);
    }
  }
}

// ---------- phase A: per-dst sums of x[src] (bf16) and edge_attr (f32, NT) -> bf16 in1[NN][128] ----------
__global__ __launch_bounds__(256) void k_aggA(const int2* __restrict__ pairs,
    const int* __restrict__ cnt,
    const unsigned short* __restrict__ xb, const float* __restrict__ ea,
    unsigned short* __restrict__ in1){
  int v = blockIdx.x*4 + (threadIdx.x>>6);
  int lane = threadIdx.x & 63;
  int slot = lane >> 4, fg = lane & 15;
  if (v >= NN) return;
  int beg = v*SLOTS;
  int end = beg + min(cnt[v], SLOTS);
  float xs[4] = {0,0,0,0}, es[4] = {0,0,0,0};
  float xt[4] = {0,0,0,0}, et[4] = {0,0,0,0};
  int i = beg + slot;
  for (; i + 12 < end; i += 16){
    int2 p0 = pairs[i],   p1 = pairs[i+4];
    int2 p2 = pairs[i+8], p3 = pairs[i+12];
    ushort4 xv0 = *(const ushort4*)(xb + (size_t)p0.x*64 + fg*4);
    ushort4 xv1 = *(const ushort4*)(xb + (size_t)p1.x*64 + fg*4);
    ushort4 xv2 = *(const ushort4*)(xb + (size_t)p2.x*64 + fg*4);
    ushort4 xv3 = *(const ushort4*)(xb + (size_t)p3.x*64 + fg*4);
    f32x4 ev0 = __builtin_nontemporal_load((const f32x4*)(ea + (size_t)p0.y*64 + fg*4));
    f32x4 ev1 = __builtin_nontemporal_load((const f32x4*)(ea + (size_t)p1.y*64 + fg*4));
    f32x4 ev2 = __builtin_nontemporal_load((const f32x4*)(ea + (size_t)p2.y*64 + fg*4));
    f32x4 ev3 = __builtin_nontemporal_load((const f32x4*)(ea + (size_t)p3.y*64 + fg*4));
    xs[0]+=bf2f(xv0.x); xs[1]+=bf2f(xv0.y); xs[2]+=bf2f(xv0.z); xs[3]+=bf2f(xv0.w);
    xt[0]+=bf2f(xv1.x); xt[1]+=bf2f(xv1.y); xt[2]+=bf2f(xv1.z); xt[3]+=bf2f(xv1.w);
    xs[0]+=bf2f(xv2.x); xs[1]+=bf2f(xv2.y); xs[2]+=bf2f(xv2.z); xs[3]+=bf2f(xv2.w);
    xt[0]+=bf2f(xv3.x); xt[1]+=bf2f(xv3.y); xt[2]+=bf2f(xv3.z); xt[3]+=bf2f(xv3.w);
    es[0]+=ev0[0]; es[1]+=ev0[1]; es[2]+=ev0[2]; es[3]+=ev0[3];
    et[0]+=ev1[0]; et[1]+=ev1[1]; et[2]+=ev1[2]; et[3]+=ev1[3];
    es[0]+=ev2[0]; es[1]+=ev2[1]; es[2]+=ev2[2]; es[3]+=ev2[3];
    et[0]+=ev3[0]; et[1]+=ev3[1]; et[2]+=ev3[2]; et[3]+=ev3[3];
  }
  for (; i < end; i += 4){
    int2 p0 = pairs[i];
    ushort4 xv0 = *(const ushort4*)(xb + (size_t)p0.x*64 + fg*4);
    f32x4  ev0 = __builtin_nontemporal_load((const f32x4*)(ea + (size_t)p0.y*64 + fg*4));
    xs[0]+=bf2f(xv0.x); xs[1]+=bf2f(xv0.y); xs[2]+=bf2f(xv0.z); xs[3]+=bf2f(xv0.w);
    es[0]+=ev0[0]; es[1]+=ev0[1]; es[2]+=ev0[2]; es[3]+=ev0[3];
  }
  #pragma unroll
  for (int k=0;k<4;k++){
    float a = xs[k] + xt[k];
    float b = es[k] + et[k];
    a += __shfl_xor(a, 16, 64); a += __shfl_xor(a, 32, 64);
    b += __shfl_xor(b, 16, 64); b += __shfl_xor(b, 32, 64);
    xs[k] = a; es[k] = b;
  }
  if (slot == 0){
    unsigned short* o = in1 + (size_t)v*128;
    ushort4 ox; ox.x=f2bf(xs[0]); ox.y=f2bf(xs[1]); ox.z=f2bf(xs[2]); ox.w=f2bf(xs[3]);
    ushort4 oe; oe.x=f2bf(es[0]); oe.y=f2bf(es[1]); oe.z=f2bf(es[2]); oe.w=f2bf(es[3]);
    *(ushort4*)(o + fg*4)      = ox;
    *(ushort4*)(o + 64 + fg*4) = oe;
  }
}

// ---------- mega kernel: h (LDS) = relu([in1|xb]@W1c^T + ...); y2 = h@W2m^T; z = h@W2s^T + ea@W2e^T + b2 folds ----------
// swizzled LDS: byte = (row*512 + col*2) ^ ((row&7)<<4)
__global__ __launch_bounds__(256) void k_mega(
  const unsigned short* __restrict__ in1, const unsigned short* __restrict__ xb,
  const unsigned short* __restrict__ W1c,
  const unsigned short* __restrict__ W2mb, const unsigned short* __restrict__ W2c,
  const float* __restrict__ b1sA, const float* __restrict__ b1dA,
  const float* __restrict__ b2sA, const float* __restrict__ b2dA,
  const int* __restrict__ cnt,
  unsigned short* __restrict__ y2, float* __restrict__ z)
{
  __shared__ char hl[64*256*2];
  const int tid = threadIdx.x;
  const int w = tid >> 6, l = tid & 63;
  const int lrow = l & 15, lgrp = l >> 4;
  const int n0 = blockIdx.x * 64;
  const int c0 = w * 64;

  // ----- phase 1: layer-1 GEMM -----
  f32x4 acc[4][4];
  #pragma unroll
  for (int i=0;i<4;i++)
    #pragma unroll
    for (int j=0;j<4;j++) acc[i][j] = (f32x4)0.f;

  #pragma unroll 2
  for (int ks=0; ks<6; ks++){
    short8 a[4], b[4];
    #pragma unroll
    for (int rf=0; rf<4; rf++){
      int row = n0 + rf*16 + lrow; if (row >= NN) row = NN-1;
      if (ks < 4) a[rf] = *(const short8*)(in1 + (size_t)row*128 + ks*32 + lgrp*8);
      else        a[rf] = *(const short8*)(xb  + (size_t)row*64 + (ks-4)*32 + lgrp*8);
    }
    #pragma unroll
    for (int cf=0; cf<4; cf++){
      b[cf] = *(const short8*)(W1c + (c0 + cf*16 + lrow)*192 + ks*32 + lgrp*8);
    }
    #pragma unroll
    for (int rf=0; rf<4; rf++)
      #pragma unroll
      for (int cf=0; cf<4; cf++)
        acc[rf][cf] = __builtin_amdgcn_mfma_f32_16x16x32_bf16(a[rf], b[cf], acc[rf][cf], 0, 0, 0);
  }

  float dg[4][4];
  #pragma unroll
  for (int rf=0; rf<4; rf++)
    #pragma unroll
    for (int r=0; r<4; r++){
      int node = n0 + rf*16 + 4*lgrp + r;
      dg[rf][r] = (node < NN) ? (float)cnt[node] : 0.f;
    }

  #pragma unroll
  for (int cf=0; cf<4; cf++){
    int oc = c0 + cf*16 + lrow;
    float bs = b1sA[oc], bd = b1dA[oc];
    #pragma unroll
    for (int rf=0; rf<4; rf++){
      #pragma unroll
      for (int r=0; r<4; r++){
        int rloc = rf*16 + 4*lgrp + r;
        float val = acc[rf][cf][r] + bs + dg[rf][r]*bd;
        val = fmaxf(val, 0.f);
        int byte = (rloc*512 + oc*2) ^ ((rloc & 7) << 4);
        *(unsigned short*)(hl + byte) = f2bf(val);
      }
    }
  }
  __syncthreads();

  // ----- phase 2: y2 = h@W2m^T ; z = h@W2s^T + ea@W2e^T (wave w -> cols w*16..w*16+15) -----
  const int oc2 = w*16 + lrow;
  f32x4 ay[4], az[4];
  #pragma unroll
  for (int i=0;i<4;i++){ ay[i] = (f32x4)0.f; az[i] = (f32x4)0.f; }

  #pragma unroll 2
  for (int ks=0; ks<8; ks++){
    short8 a2[4];
    #pragma unroll
    for (int rf=0; rf<4; rf++){
      int rloc = rf*16 + lrow;
      int byte = (rloc*512 + (ks*32 + lgrp*8)*2) ^ ((rloc & 7) << 4);
      a2[rf] = *(const short8*)(hl + byte);
    }
    short8 by = *(const short8*)(W2mb + oc2*256 + ks*32 + lgrp*8);
    short8 bz = *(const short8*)(W2c  + oc2*320 + 64 + ks*32 + lgrp*8);
    #pragma unroll
    for (int rf=0; rf<4; rf++){
      ay[rf] = __builtin_amdgcn_mfma_f32_16x16x32_bf16(a2[rf], by, ay[rf], 0, 0, 0);
      az[rf] = __builtin_amdgcn_mfma_f32_16x16x32_bf16(a2[rf], bz, az[rf], 0, 0, 0);
    }
  }
  #pragma unroll
  for (int ks=0; ks<2; ks++){
    short8 a3[4];
    #pragma unroll
    for (int rf=0; rf<4; rf++){
      int row = n0 + rf*16 + lrow; if (row >= NN) row = NN-1;
      a3[rf] = *(const short8*)(in1 + (size_t)row*128 + 64 + ks*32 + lgrp*8);
    }
    short8 be = *(const short8*)(W2c + oc2*320 + ks*32 + lgrp*8);
    #pragma unroll
    for (int rf=0; rf<4; rf++)
      az[rf] = __builtin_amdgcn_mfma_f32_16x16x32_bf16(a3[rf], be, az[rf], 0, 0, 0);
  }

  float bs2 = b2sA[oc2], bd2 = b2dA[oc2];
  #pragma unroll
  for (int rf=0; rf<4; rf++){
    #pragma unroll
    for (int r=0; r<4; r++){
      int node = n0 + rf*16 + 4*lgrp + r;
      if (node < NN){
        y2[(size_t)node*64 + oc2] = f2bf(ay[rf][r]);
        z[(size_t)node*64 + oc2]  = az[rf][r] + bs2 + dg[rf][r]*bd2;
      }
    }
  }
}

// ---------- final: agg2 = per-dst sum of y2[src]; out = relu(z + agg2) ----------
__global__ __launch_bounds__(256) void k_aggC(const int2* __restrict__ pairs, const int* __restrict__ cnt,
    const unsigned short* __restrict__ y2, const float* __restrict__ z, float* __restrict__ out){
  int v = blockIdx.x*4 + (threadIdx.x>>6);
  int lane = threadIdx.x & 63;
  int slot = lane >> 4, fg = lane & 15;
  if (v >= NN) return;
  int beg = v*SLOTS;
  int end = beg + min(cnt[v], SLOTS);
  float a[4] = {0,0,0,0}, b[4] = {0,0,0,0};
  int i = beg + slot;
  for (; i + 12 < end; i += 16){
    int s0 = pairs[i].x, s1 = pairs[i+4].x, s2 = pairs[i+8].x, s3 = pairs[i+12].x;
    ushort4 y0 = *(const ushort4*)(y2 + (size_t)s0*64 + fg*4);
    ushort4 y1 = *(const ushort4*)(y2 + (size_t)s1*64 + fg*4);
    ushort4 y2v = *(const ushort4*)(y2 + (size_t)s2*64 + fg*4);
    ushort4 y3 = *(const ushort4*)(y2 + (size_t)s3*64 + fg*4);
    a[0]+=bf2f(y0.x); a[1]+=bf2f(y0.y); a[2]+=bf2f(y0.z); a[3]+=bf2f(y0.w);
    b[0]+=bf2f(y1.x); b[1]+=bf2f(y1.y); b[2]+=bf2f(y1.z); b[3]+=bf2f(y1.w);
    a[0]+=bf2f(y2v.x); a[1]+=bf2f(y2v.y); a[2]+=bf2f(y2v.z); a[3]+=bf2f(y2v.w);
    b[0]+=bf2f(y3.x); b[1]+=bf2f(y3.y); b[2]+=bf2f(y3.z); b[3]+=bf2f(y3.w);
  }
  for (; i < end; i += 4){
    int s0 = pairs[i].x;
    ushort4 y0 = *(const ushort4*)(y2 + (size_t)s0*64 + fg*4);
    a[0]+=bf2f(y0.x); a[1]+=bf2f(y0.y); a[2]+=bf2f(y0.z); a[3]+=bf2f(y0.w);
  }
  #pragma unroll
  for (int k=0;k<4;k++){
    float t = a[k] + b[k];
    t += __shfl_xor(t, 16, 64); t += __shfl_xor(t, 32, 64);
    a[k] = t;
  }
  if (slot == 0){
    const float4 zv = *(const float4*)(z + (size_t)v*64 + fg*4);
    f32x4 o;
    o[0] = fmaxf(zv.x + a[0], 0.f);
    o[1] = fmaxf(zv.y + a[1], 0.f);
    o[2] = fmaxf(zv.z + a[2], 0.f);
    o[3] = fmaxf(zv.w + a[3], 0.f);
    __builtin_nontemporal_store(o, (f32x4*)(out + (size_t)v*64 + fg*4));
  }
}

extern "C" void kernel_launch(void* const* d_in, const int* in_sizes, int n_in,
                              void* d_out, int out_size, void* d_ws, size_t ws_size,
                              hipStream_t stream){
  const float* x   = (const float*)d_in[0];
  const int*   ei  = (const int*)d_in[1];
  const float* ea  = (const float*)d_in[2];
  const float* W1m = (const float*)d_in[3];  const float* b1m = (const float*)d_in[4];
  const float* W1e = (const float*)d_in[5];  const float* b1e = (const float*)d_in[6];
  const float* W1s = (const float*)d_in[7];  const float* b1s = (const float*)d_in[8];
  const float* W2m = (const float*)d_in[9];  const float* b2m = (const float*)d_in[10];
  const float* W2e = (const float*)d_in[11]; const float* b2e = (const float*)d_in[12];
  const float* W2s = (const float*)d_in[13]; const float* b2s = (const float*)d_in[14];
  float* out = (float*)d_out;

  char* base = (char*)d_ws;
  size_t off = 0;
  auto alloc = [&](size_t bytes)->void* {
    void* r = base + off;
    off += (bytes + 255) & ~(size_t)255;
    return r;
  };
  int*   cnt       = (int*)  alloc((size_t)NN*4);
  int2*  pairs_pad = (int2*) alloc(((size_t)NN*SLOTS + SLOTS)*8);   // padded buckets
  unsigned short* in1 = (unsigned short*)alloc((size_t)NN*128*2);   // [xs|ea] bf16
  unsigned short* y2  = (unsigned short*)alloc((size_t)NN*64*2);
  float*          z   = (float*)         alloc((size_t)NN*64*4);
  unsigned short* xb  = (unsigned short*)alloc((size_t)NN*64*2);
  unsigned short* W1c = (unsigned short*)alloc((size_t)256*192*2);
  unsigned short* W2c = (unsigned short*)alloc((size_t)64*320*2);
  unsigned short* W2mb= (unsigned short*)alloc((size_t)64*256*2);
  float* b1sA = (float*)alloc(256*4);
  float* b1dA = (float*)alloc(256*4);
  float* b2sA = (float*)alloc(64*4);
  float* b2dA = (float*)alloc(64*4);

  k_prep    <<<(NN*8+255)/256, 256, 0, stream>>>(x, W1m,b1m,W1e,b1e,W1s,b1s,
                                               W2m,b2m,W2e,b2e,W2s,b2s,
                                               cnt, xb, W1c, W2c, W2mb,
                                               b1sA,b1dA,b2sA,b2dA);
  k_scatter1<<<(NE/4+255)/256, 256, 0, stream>>>(ei, cnt, pairs_pad);
  k_aggA    <<<(NN+3)/4, 256, 0, stream>>>(pairs_pad, cnt, xb, ea, in1);
  k_mega    <<<(NN+63)/64, 256, 0, stream>>>(in1, xb, W1c, W2mb, W2c,
                                             b1sA, b1dA, b2sA, b2dA, cnt, y2, z);
  k_aggC    <<<(NN+3)/4, 256, 0, stream>>>(pairs_pad, cnt, y2, z, out);
}